// Round 3
// baseline (85.806 us; speedup 1.0000x reference)
//
#include <hip/hip_runtime.h>
#include <math.h>

#define EPS2f 0.25f
#define EPS4f 0.0625f

// readlane with compile-time lane: wave-uniform broadcast from a register,
// result lands in an SGPR (free operand on the consuming v_fma).
__device__ __forceinline__ float rl(float v, int l) {
    return __int_as_float(__builtin_amdgcn_readlane(__float_as_int(v), l));
}

// ---------------------------------------------------------------------------
// Kernel 1: precompute per-(ij,k) tables (unchanged layouts).
//   AB4 (float4 view)[k2*1024 + ij] = { A(2k2), B2(2k2), A(2k2+1), B2(2k2+1) }
//        A = 1/Sigma, B2 = 2*mu_t/Sigma
//   KV4 (float4 view)[ij2*64 + k]   = { K(ij_e), Vm(ij_e), K(ij_o), Vm(ij_o) }
//   C0 [ij] = sum_k ( mu_t^2/Sigma + log(Sigma) )
// ---------------------------------------------------------------------------
__global__ __launch_bounds__(256) void precomp_kernel(
    const float* __restrict__ Mu0, const float* __restrict__ Mu1,
    const float* __restrict__ S0,  const float* __restrict__ S1,
    const float* __restrict__ tptr,
    float2* __restrict__ AB2, float2* __restrict__ KV2,
    float* __restrict__ C0)
{
    __shared__ float2 abS[4][67];
    __shared__ float2 kvS[4][64];

    const int tid = threadIdx.x;
    const int k   = tid & 63;
    const int ijl = tid >> 6;
    const int ij0 = blockIdx.x << 2;
    const int ij  = ij0 + ijl;
    const int i   = ij >> 5;
    const int j   = ij & 31;
    const float t   = *tptr;
    const float omt = 1.0f - t;

    const float s0 = S0[i * 64 + k];
    const float s1 = S1[j * 64 + k];
    const float m0 = Mu0[i * 64 + k];
    const float m1 = Mu1[j * 64 + k];

    const float ds  = sqrtf(4.0f * s0 * s1 + EPS4f);
    const float cs  = 0.5f * (ds - EPS2f);
    const float mt  = omt * m0 + t * m1;
    const float sig = omt * omt * s0 + t * t * s1
                    + 2.0f * t * omt * (cs + 0.5f * EPS2f);
    const float isig = 1.0f / sig;
    const float st = t * s1 - omt * s0 + (omt - t) * cs - EPS2f * t;
    const float kk = st * isig;
    const float v  = m1 - m0;

    abS[ijl][k] = make_float2(isig, 2.0f * mt * isig);
    kvS[ijl][k] = make_float2(kk, v - kk * mt);

    float c = mt * mt * isig + __logf(sig);
    #pragma unroll
    for (int off = 32; off >= 1; off >>= 1)
        c += __shfl_xor(c, off, 64);
    if (k == 0) C0[ij] = c;

    __syncthreads();

    {   // AB store: tid = k2*8 + ijl2*2 + par -> 64B-chunked, near-coalesced
        const int k2   = tid >> 3;
        const int ijl2 = (tid >> 1) & 3;
        const int par  = tid & 1;
        AB2[(k2 << 11) + ((ij0 + ijl2) << 1) + par] = abS[ijl2][2 * k2 + par];
    }
    {   // KV store: fully linear in tid (bijection with consumer layout)
        const int pr  = tid >> 7;
        const int k6  = (tid >> 1) & 63;
        const int par = tid & 1;
        KV2[(blockIdx.x << 8) + tid] = kvS[(pr << 1) + par][k6];
    }
}

// ---------------------------------------------------------------------------
// Kernel 2: main, restructured to amortize table bytes 8x.
// Grid 512 blocks x 256 threads; each wave is fully independent:
//   wave = 8 batch rows x 64 ij (one ij-chunk). Block = 4 waves = 32 rows.
// Per 16B table load: 32 FMA (8 rows), vs 16 before -> unique table traffic
// per block drops from 1 MiB to 64 KiB (total L2: 256 MiB -> 32 MiB; per-CU
// L1 misses 1 MiB -> 128 KiB). W never leaves the wave (readlane), X is
// lane-resident for BOTH phases (lane=ij in A, lane=k in B). No LDS, no
// barriers. Per-chunk partials go to workspace; kernel 3 combines.
// ---------------------------------------------------------------------------
__global__ __launch_bounds__(256) void gmm_main_kernel(
    const float* __restrict__ X,   const float* __restrict__ Lam,
    const float* __restrict__ C0,
    const float4* __restrict__ AB4, const float4* __restrict__ KV4,
    float* __restrict__ nump, float* __restrict__ denp)
{
    const int tid    = threadIdx.x;
    const int lane   = tid & 63;
    const int rowsub = tid >> 6;               // 0..3
    const int bx     = blockIdx.x;
    const int c      = bx & 15;                // ij-chunk of 64
    const int g      = bx >> 4;                // rowgroup of 32 (0..31)
    const int r0     = (g << 5) + (rowsub << 3); // this wave's first row
    const int ij     = (c << 6) + lane;

    // per-lane X for this wave's 8 rows (serves phase A via readlane and
    // phase B directly, since lane=k there)
    float xr[8];
    #pragma unroll
    for (int u = 0; u < 8; ++u) xr[u] = X[(r0 + u) * 64 + lane];

    const float c0 = C0[ij];
    const float lm = Lam[ij];

    // ---- Phase A: logits for 8 rows at this lane's ij ----
    const float4* __restrict__ abp = AB4 + ij;     // + k2*1024
    float4 ab[4];
    #pragma unroll
    for (int pf = 0; pf < 4; ++pf) ab[pf] = abp[pf << 10];

    float q[8] = {0.f, 0.f, 0.f, 0.f, 0.f, 0.f, 0.f, 0.f};
    #pragma unroll
    for (int k2 = 0; k2 < 32; ++k2) {
        const float4 a = ab[k2 & 3];
        if (k2 + 4 < 32) ab[k2 & 3] = abp[(k2 + 4) << 10];
        #pragma unroll
        for (int u = 0; u < 8; ++u) {
            const float xe = rl(xr[u], 2 * k2);
            const float xo = rl(xr[u], 2 * k2 + 1);
            q[u] = fmaf(fmaf(a.x, xe, -a.y), xe, q[u]);
            q[u] = fmaf(fmaf(a.z, xo, -a.w), xo, q[u]);
        }
    }

    float wv[8];
    #pragma unroll
    for (int u = 0; u < 8; ++u)
        wv[u] = __expf(fminf(fmaxf(-0.5f * (q[u] + c0), -50.f), 50.f)) * lm;

    // ---- Phase B prologue: first KV loads fly under the den reduction ----
    const float4* __restrict__ kvp = KV4 + (c << 11) + lane;  // + p*64
    float4 kvb[4];
    #pragma unroll
    for (int pf = 0; pf < 4; ++pf) kvb[pf] = kvp[pf << 6];

    // den partial: sum wv[u] over the wave's 64 ij (butterfly; all lanes end
    // with the total)
    float dsum[8];
    #pragma unroll
    for (int u = 0; u < 8; ++u) dsum[u] = wv[u];
    #pragma unroll
    for (int off = 32; off >= 1; off >>= 1) {
        #pragma unroll
        for (int u = 0; u < 8; ++u) dsum[u] += __shfl_xor(dsum[u], off, 64);
    }

    // ---- Phase B: lane = k, loop this chunk's 32 ij-pairs ----
    float nacc[8] = {0.f, 0.f, 0.f, 0.f, 0.f, 0.f, 0.f, 0.f};
    #pragma unroll
    for (int p = 0; p < 32; ++p) {
        const float4 kv = kvb[p & 3];
        if (p + 4 < 32) kvb[p & 3] = kvp[(p + 4) << 6];
        #pragma unroll
        for (int u = 0; u < 8; ++u) {
            const float We = rl(wv[u], 2 * p);
            const float Wo = rl(wv[u], 2 * p + 1);
            const float ue = fmaf(kv.x, xr[u], kv.y);
            nacc[u] = fmaf(We, ue, nacc[u]);
            const float uo = fmaf(kv.z, xr[u], kv.w);
            nacc[u] = fmaf(Wo, uo, nacc[u]);
        }
    }

    // ---- Write per-chunk partials (no LDS, no barrier) ----
    #pragma unroll
    for (int u = 0; u < 8; ++u)
        nump[(c * 1024 + r0 + u) * 64 + lane] = nacc[u];   // coalesced 256B

    float dv = dsum[0];
    #pragma unroll
    for (int u = 1; u < 8; ++u) dv = (lane == u) ? dsum[u] : dv;
    if (lane < 8) denp[(c << 10) + r0 + lane] = dv;
}

// ---------------------------------------------------------------------------
// Kernel 3: combine 16 chunk-partials and divide. ~8.6 MiB of L2 reads.
// ---------------------------------------------------------------------------
__global__ __launch_bounds__(256) void combine_kernel(
    const float* __restrict__ nump, const float* __restrict__ denp,
    float* __restrict__ out)
{
    const int idx = blockIdx.x * 256 + threadIdx.x;  // 0..65535
    const int b = idx >> 6;
    const int k = idx & 63;
    float s = 0.f, d = 0.f;
    #pragma unroll
    for (int c = 0; c < 16; ++c) {
        s += nump[(c * 1024 + b) * 64 + k];
        d += denp[(c << 10) + b];
    }
    out[idx] = s / d;
}

extern "C" void kernel_launch(void* const* d_in, const int* in_sizes, int n_in,
                              void* d_out, int out_size, void* d_ws, size_t ws_size,
                              hipStream_t stream) {
    const float* X   = (const float*)d_in[0];
    const float* Mu0 = (const float*)d_in[1];
    const float* Mu1 = (const float*)d_in[2];
    const float* S0  = (const float*)d_in[3];
    const float* S1  = (const float*)d_in[4];
    const float* Lam = (const float*)d_in[5];
    const float* t   = (const float*)d_in[6];
    float* out = (float*)d_out;

    char* ws = (char*)d_ws;
    float2* AB2  = (float2*)(ws);                  // 512 KiB
    float2* KV2  = (float2*)(ws + (512 << 10));    // 512 KiB
    float*  C0   = (float*)(ws + (1024 << 10));    // 4 KiB
    float*  nump = (float*)(ws + (2 << 20));       // 16*1024*64*4 = 4 MiB
    float*  denp = (float*)(ws + (6 << 20));       // 16*1024*4   = 64 KiB

    precomp_kernel<<<256, 256, 0, stream>>>(Mu0, Mu1, S0, S1, t, AB2, KV2, C0);
    gmm_main_kernel<<<512, 256, 0, stream>>>(X, Lam, C0,
                                             (const float4*)AB2,
                                             (const float4*)KV2, nump, denp);
    combine_kernel<<<256, 256, 0, stream>>>(nump, denp, out);
}